// Round 2
// baseline (185.830 us; speedup 1.0000x reference)
//
#include <hip/hip_runtime.h>

// Problem: tensor [8192, 64, 64] fp32.
// Per batch b: (mx,my) = argmax location; loss = sum_b sum_{j,k} ((mx-j)^2+(my-k)^2)*v.
//
// Moments trick: loss_b = (mx^2+my^2)*S - 2*mx*Sj - 2*my*Sk + Sd2
// with S=Σv, Sj=Σ j·v, Sk=Σ k·v, Sd2=Σ (j²+k²)·v — all independent of the argmax,
// so one pass computes moments + argmax concurrently, one barrier per block.

#define NB   8192   // batches
#define HW   4096   // 64*64 per batch
#define TPB  256    // threads per block (4 waves)
#define VPT  4      // float4 loads per thread -> 16 elements per thread

__global__ __launch_bounds__(TPB) void loss_main_kernel(
    const float* __restrict__ in, float* __restrict__ partial) {
    const int b = blockIdx.x;
    const int t = threadIdx.x;
    const int wave = t >> 6;
    const int lane = t & 63;

    const float4* base = (const float4*)(in + (size_t)b * HW);

    // Issue all 4 global loads up front (4 outstanding dwordx4 per lane).
    float4 v[VPT];
#pragma unroll
    for (int i = 0; i < VPT; ++i) v[i] = base[i * TPB + t];

    // One pass: 4 moments + argmax. No cross-barrier register liveness.
    float S = 0.f, Sj = 0.f, Sk = 0.f, Sd = 0.f;
    float best = -1.f;
    int   bidx = 0;
#pragma unroll
    for (int i = 0; i < VPT; ++i) {
        const int fi = (i * TPB + t) * 4;   // flat index of v[i].x
        const float fj  = (float)(fi >> 6); // row (shared by all 4 lanes' elems)
        const float fj2 = fj * fj;
        const float kb  = (float)(fi & 63);
        const float vals[4] = {v[i].x, v[i].y, v[i].z, v[i].w};
#pragma unroll
        for (int c = 0; c < 4; ++c) {
            const float val = vals[c];
            const float fk  = kb + (float)c;
            S  += val;
            Sj  = fmaf(fj, val, Sj);
            Sk  = fmaf(fk, val, Sk);
            Sd  = fmaf(fj2 + fk * fk, val, Sd);
            if (val > best) { best = val; bidx = fi + c; }  // ascending idx => first occurrence
        }
    }

    // Wave64 reduction: 4 sums + argmax (tie-break: lower index).
#pragma unroll
    for (int off = 32; off > 0; off >>= 1) {
        S  += __shfl_down(S,  off, 64);
        Sj += __shfl_down(Sj, off, 64);
        Sk += __shfl_down(Sk, off, 64);
        Sd += __shfl_down(Sd, off, 64);
        const float oval = __shfl_down(best, off, 64);
        const int   oidx = __shfl_down(bidx, off, 64);
        if (oval > best || (oval == best && oidx < bidx)) { best = oval; bidx = oidx; }
    }

    // Cross-wave merge: single barrier.
    __shared__ float sS[4], sSj[4], sSk[4], sSd[4], sBest[4];
    __shared__ int   sIdx[4];
    if (lane == 0) {
        sS[wave] = S; sSj[wave] = Sj; sSk[wave] = Sk; sSd[wave] = Sd;
        sBest[wave] = best; sIdx[wave] = bidx;
    }
    __syncthreads();
    if (t == 0) {
        float tS = sS[0], tSj = sSj[0], tSk = sSk[0], tSd = sSd[0];
        float bb = sBest[0]; int bi = sIdx[0];
#pragma unroll
        for (int w = 1; w < 4; ++w) {
            tS += sS[w]; tSj += sSj[w]; tSk += sSk[w]; tSd += sSd[w];
            if (sBest[w] > bb || (sBest[w] == bb && sIdx[w] < bi)) { bb = sBest[w]; bi = sIdx[w]; }
        }
        const float mx = (float)(bi >> 6);
        const float my = (float)(bi & 63);
        partial[b] = (mx * mx + my * my) * tS - 2.f * mx * tSj - 2.f * my * tSk + tSd;
    }
}

// Reduce 8192 per-block partials -> out[0]. Unconditionally overwrites d_out
// (handles the 0xAA re-poison before each timed launch).
__global__ __launch_bounds__(TPB) void loss_reduce_kernel(
    const float* __restrict__ partial, float* __restrict__ out) {
    const int t = threadIdx.x;
    const float4* p4 = (const float4*)partial;
    float acc = 0.0f;
#pragma unroll
    for (int i = 0; i < NB / (TPB * 4); ++i) {  // 8 float4 per thread
        const float4 p = p4[i * TPB + t];
        acc += (p.x + p.y) + (p.z + p.w);
    }
#pragma unroll
    for (int off = 32; off > 0; off >>= 1) acc += __shfl_down(acc, off, 64);
    __shared__ float s[4];
    const int wave = t >> 6, lane = t & 63;
    if (lane == 0) s[wave] = acc;
    __syncthreads();
    if (t == 0) out[0] = (s[0] + s[1]) + (s[2] + s[3]);
}

extern "C" void kernel_launch(void* const* d_in, const int* in_sizes, int n_in,
                              void* d_out, int out_size, void* d_ws, size_t ws_size,
                              hipStream_t stream) {
    const float* in = (const float*)d_in[0];
    float* out = (float*)d_out;
    float* partial = (float*)d_ws;  // needs NB*4 = 32 KB

    loss_main_kernel<<<NB, TPB, 0, stream>>>(in, partial);
    loss_reduce_kernel<<<1, TPB, 0, stream>>>(partial, out);
}